// Round 8
// baseline (102.200 us; speedup 1.0000x reference)
//
#include <hip/hip_runtime.h>

// YOLO loss: S=1024, 30 f32 channels/cell, channel-last contiguous.
// loss = 5*xy + 5*box + (conf_t-conf_p)^2 + cls_masked
//
// R1: coalesced LDS staging fixed 3.25x over-fetch (236 -> 46.8us).
// R2: occupancy 19->42% flat (45.2us) -> convoy/latency, not occupancy.
// R4/R7: held-register prefetch spilled to scratch BOTH times (WRITE_SIZE
//   217-240MB, FETCH flat -> spill writes leak to HBM, reloads hit L2).
//   VGPR_Count=88 shows hipcc refused to budget regs for r[8] without a
//   launch-bounds contract.
// R5/R6: global_load_lds variants NaN'd twice -> dropped (unvalidated).
// R8: R7 unchanged except __launch_bounds__(256, 2): VGPR cap 256 so the
//   8x float4 prefetch stays in registers. LDS already caps at 2 blocks/CU,
//   so the register contract costs no occupancy.

constexpr int CH         = 30;
constexpr int NCELL      = 1024 * 1024;
constexpr int BLOCK      = 256;
constexpr int TILE_CELLS = 128;
constexpr int TILE_F4    = TILE_CELLS * CH / 4;   // 960 float4 per tensor
constexpr int GRID       = 512;                   // 2 blocks/CU resident
constexpr int NTILES     = NCELL / TILE_CELLS;    // 8192
constexpr int NIT        = NTILES / GRID;         // 16 tiles per block

__device__ __forceinline__ float wave_reduce_sum(float v) {
#pragma unroll
    for (int off = 32; off > 0; off >>= 1)
        v += __shfl_down(v, off, 64);
    return v;
}

__global__ __launch_bounds__(BLOCK, 2) void yolo_partial_kernel(
        const float* __restrict__ pred,
        const float* __restrict__ tgt,
        float* __restrict__ partial) {
    // [buffer][pred f4 0..959 | tgt f4 960..1919] : 61,440 B -> 2 blocks/CU
    __shared__ float4 sbuf[2][2 * TILE_F4];

    const int tid  = threadIdx.x;
    const int wv   = tid >> 6;
    const int ln   = tid & 63;
    const int cell = tid >> 1;        // 0..127
    const int half = tid & 1;         // which box / class half

    const float4* pf4 = reinterpret_cast<const float4*>(pred);
    const float4* tf4 = reinterpret_cast<const float4*>(tgt);

    // Staging split over the combined 1920-f4 tile in 64-f4 chunks:
    // wave0 chunks 0..7, wave1 8..15, wave2 16..22, wave3 23..29 (8,8,7,7).
    // 960 % 64 == 0, so every chunk lies entirely in one tensor.
    const int c0 = (wv < 2) ? wv * 8 : 16 + (wv - 2) * 7;

    float4 r[8];

    auto load_tile = [&](int tile) {
        const size_t tb = (size_t)tile * TILE_F4;
        if (wv < 2) {
#pragma unroll
            for (int k = 0; k < 8; ++k) {
                const int ci = (c0 + k) * 64;
                r[k] = (ci < TILE_F4) ? pf4[tb + ci + ln]
                                      : tf4[tb + (ci - TILE_F4) + ln];
            }
        } else {
#pragma unroll
            for (int k = 0; k < 7; ++k) {
                const int ci = (c0 + k) * 64;   // >= 1024 -> always tgt
                r[k] = tf4[tb + (ci - TILE_F4) + ln];
            }
        }
    };
    auto store_tile = [&](int b) {
        if (wv < 2) {
#pragma unroll
            for (int k = 0; k < 8; ++k) sbuf[b][(c0 + k) * 64 + ln] = r[k];
        } else {
#pragma unroll
            for (int k = 0; k < 7; ++k) sbuf[b][(c0 + k) * 64 + ln] = r[k];
        }
    };

    int t = blockIdx.x;
    load_tile(t);          // prologue: tile 0 -> regs -> buf0
    store_tile(0);
    __syncthreads();

    float acc = 0.0f;
    for (int it = 0; it < NIT; ++it) {
        const int cur = it & 1;
        const bool havenext = (it + 1 < NIT);

        if (havenext) load_tile(t + GRID);      // issue early: hides under compute
        __builtin_amdgcn_sched_barrier(0);       // keep loads above compute

        const float* bf = reinterpret_cast<const float*>(&sbuf[cur][0]);
        const float* pp = bf + cell * CH;
        const float* tt = bf + TILE_F4 * 4 + cell * CH;

        // this thread's box: channels [5*half .. 5*half+4] = (conf,x,y,w,h)
        {
            const int o = 5 * half;
            const float conf_p = pp[o + 0];
            const float x_p    = pp[o + 1];
            const float y_p    = pp[o + 2];
            const float w_p    = sqrtf(fabsf(pp[o + 3]));
            const float h_p    = sqrtf(fabsf(pp[o + 4]));
            const float conf_t = tt[o + 0];
            const float x_t    = tt[o + 1];
            const float y_t    = tt[o + 2];
            const float w_t    = sqrtf(tt[o + 3]);
            const float h_t    = sqrtf(tt[o + 4]);

            const float dx = x_t - x_p, dy = y_t - y_p;
            const float dw = w_t - w_p, dh = h_t - h_p;
            const float dc = conf_t - conf_p;

            acc += 5.0f * ((dx * dx + dy * dy) * conf_t)
                 + 5.0f * ((dw * dw + dh * dh) * conf_t)
                 + dc * dc;
        }

        // this thread's class half: channels [10+10*half ..+9]; the mask
        // needs the FULL 20-channel target sum -> combine across lane pair.
        {
            float ssum = 0.0f, per_cell = 0.0f;
            const int co = 10 + 10 * half;
#pragma unroll
            for (int k = 0; k < 10; ++k) {
                const float tc = tt[co + k];
                const float pc = pp[co + k];
                ssum     += tc;
                per_cell += tc * tc - pc * pc;
            }
            const float tot = ssum + __shfl_xor(ssum, 1, 64);
            acc += (tot == 1.0f) ? per_cell : 0.0f;
        }

        // stage tile t+GRID into the other buffer. Its previous readers
        // finished before last iteration's barrier -> safe.
        if (havenext) store_tile(cur ^ 1);
        __syncthreads();
        t += GRID;
    }

    // block reduction: wave shuffle -> LDS across 4 waves
    __shared__ float red[BLOCK / 64];
    float v = wave_reduce_sum(acc);
    if (ln == 0) red[wv] = v;
    __syncthreads();
    if (wv == 0) {
        v = (ln < (BLOCK / 64)) ? red[ln] : 0.0f;
        v = wave_reduce_sum(v);
        if (ln == 0) partial[blockIdx.x] = v;
    }
}

__global__ __launch_bounds__(256) void yolo_final_kernel(
        const float* __restrict__ partial,
        float* __restrict__ out,
        int n) {
    float acc = 0.0f;
    for (int i = threadIdx.x; i < n; i += 256)
        acc += partial[i];

    __shared__ float red[4];
    const int lane = threadIdx.x & 63;
    const int wid  = threadIdx.x >> 6;
    float v = wave_reduce_sum(acc);
    if (lane == 0) red[wid] = v;
    __syncthreads();
    if (wid == 0) {
        v = (lane < 4) ? red[lane] : 0.0f;
        v = wave_reduce_sum(v);
        if (lane == 0) out[0] = v;
    }
}

extern "C" void kernel_launch(void* const* d_in, const int* in_sizes, int n_in,
                              void* d_out, int out_size, void* d_ws, size_t ws_size,
                              hipStream_t stream) {
    const float* pred = (const float*)d_in[0];
    const float* tgt  = (const float*)d_in[1];
    float* out        = (float*)d_out;
    float* partial    = (float*)d_ws;   // GRID floats = 2 KB

    yolo_partial_kernel<<<GRID, BLOCK, 0, stream>>>(pred, tgt, partial);
    yolo_final_kernel<<<1, 256, 0, stream>>>(partial, out, GRID);
}

// Round 9
// 42.918 us; speedup vs baseline: 2.3813x; 2.3813x over previous
//
#include <hip/hip_runtime.h>

// YOLO loss: S=1024, 30 f32 channels/cell, channel-last contiguous.
// loss = 5*xy + 5*box + (conf_t-conf_p)^2 + cls_masked
//
// R1: coalesced LDS staging fixed 3.25x over-fetch (236 -> 46.8us).
// R2: occupancy 19->42% flat (45.2us) -> convoy/latency, not occupancy.
// R4/R7/R8: array-based register prefetch never got promoted (VGPR stuck at
//   88 regardless of launch_bounds; WRITE_SIZE 217-240MB scratch leak).
//   Cause: r[8] captured by-ref in lambdas w/ divergent 8-vs-7 branches ->
//   SROA failure, scratch from birth. NOT a budget problem.
// R5/R6: global_load_lds variants NaN'd twice -> dropped.
// R9: R7 pipeline, staging rewritten as straight-line NAMED scalars:
//   per tensor per thread 3xfloat4 + 1xfloat2 + 1xfloat (3840 floats =
//   256*(12+2+1) exactly). No arrays, no lambdas, no divergence.
//   Loop: [issue tile k+1 loads] [compute tile k from LDS] [ds_write k+1]
//   [barrier] -- loads get the whole compute phase to land.

constexpr int CH         = 30;
constexpr int NCELL      = 1024 * 1024;
constexpr int BLOCK      = 256;
constexpr int TILE_CELLS = 128;
constexpr int TPF        = TILE_CELLS * CH;       // 3840 floats per tensor
constexpr int GRID       = 512;                   // 2 blocks/CU resident
constexpr int NTILES     = NCELL / TILE_CELLS;    // 8192
constexpr int NIT        = NTILES / GRID;         // 16 tiles per block

__device__ __forceinline__ float wave_reduce_sum(float v) {
#pragma unroll
    for (int off = 32; off > 0; off >>= 1)
        v += __shfl_down(v, off, 64);
    return v;
}

__global__ __launch_bounds__(BLOCK, 2) void yolo_partial_kernel(
        const float* __restrict__ pred,
        const float* __restrict__ tgt,
        float* __restrict__ partial) {
    // [buf][pred floats 0..3839 | tgt floats 3840..7679] : 61,440 B total
    __shared__ float4 sbuf4[2][2 * TPF / 4];

    const int tid  = threadIdx.x;
    const int wv   = tid >> 6;
    const int ln   = tid & 63;
    const int cell = tid >> 1;        // 0..127
    const int half = tid & 1;         // which box / class half

    // Named staging registers: 3 float4 + 1 float2 + 1 float per tensor.
    float4 p0, p1, p2, t0, t1, t2;
    float2 p3, t3;
    float  p4, t4;

    // Per-thread source offsets (floats): f4 part j*1024+tid*4, f2 part
    // 3072+tid*2, f1 part 3584+tid. All lane-contiguous per instruction.
#define LOAD_TILE(tile)                                                      \
    do {                                                                     \
        const size_t tb = (size_t)(tile) * TPF;                              \
        const float4* pf4 = reinterpret_cast<const float4*>(pred + tb);      \
        const float4* tf4 = reinterpret_cast<const float4*>(tgt  + tb);      \
        const float2* pf2 = reinterpret_cast<const float2*>(pred + tb);      \
        const float2* tf2 = reinterpret_cast<const float2*>(tgt  + tb);      \
        p0 = pf4[0 * 256 + tid];  t0 = tf4[0 * 256 + tid];                   \
        p1 = pf4[1 * 256 + tid];  t1 = tf4[1 * 256 + tid];                   \
        p2 = pf4[2 * 256 + tid];  t2 = tf4[2 * 256 + tid];                   \
        p3 = pf2[1536 + tid];     t3 = tf2[1536 + tid];                      \
        p4 = pred[tb + 3584 + tid]; t4 = tgt[tb + 3584 + tid];               \
    } while (0)

#define STORE_TILE(b)                                                        \
    do {                                                                     \
        float*  sf  = reinterpret_cast<float*>(&sbuf4[(b)][0]);              \
        float4* sp4 = reinterpret_cast<float4*>(sf);                         \
        float4* st4 = reinterpret_cast<float4*>(sf + TPF);                   \
        float2* sp2 = reinterpret_cast<float2*>(sf);                         \
        float2* st2 = reinterpret_cast<float2*>(sf + TPF);                   \
        sp4[0 * 256 + tid] = p0;  st4[0 * 256 + tid] = t0;                   \
        sp4[1 * 256 + tid] = p1;  st4[1 * 256 + tid] = t1;                   \
        sp4[2 * 256 + tid] = p2;  st4[2 * 256 + tid] = t2;                   \
        sp2[1536 + tid] = p3;     st2[1536 + tid] = t3;                      \
        sf[3584 + tid] = p4;      sf[TPF + 3584 + tid] = t4;                 \
    } while (0)

    int t = blockIdx.x;
    LOAD_TILE(t);              // prologue: tile 0 -> regs -> buf0
    STORE_TILE(0);
    __syncthreads();

    float acc = 0.0f;
    for (int it = 0; it < NIT; ++it) {
        const int cur = it & 1;
        const bool havenext = (it + 1 < NIT);

        if (havenext) LOAD_TILE(t + GRID);   // in flight during compute below
        __builtin_amdgcn_sched_barrier(0);    // pin loads above compute

        const float* bf = reinterpret_cast<const float*>(&sbuf4[cur][0]);
        const float* pp = bf + cell * CH;
        const float* tt = bf + TPF + cell * CH;

        // this thread's box: channels [5*half .. 5*half+4] = (conf,x,y,w,h)
        {
            const int o = 5 * half;
            const float conf_p = pp[o + 0];
            const float x_p    = pp[o + 1];
            const float y_p    = pp[o + 2];
            const float w_p    = sqrtf(fabsf(pp[o + 3]));
            const float h_p    = sqrtf(fabsf(pp[o + 4]));
            const float conf_t = tt[o + 0];
            const float x_t    = tt[o + 1];
            const float y_t    = tt[o + 2];
            const float w_t    = sqrtf(tt[o + 3]);
            const float h_t    = sqrtf(tt[o + 4]);

            const float dx = x_t - x_p, dy = y_t - y_p;
            const float dw = w_t - w_p, dh = h_t - h_p;
            const float dc = conf_t - conf_p;

            acc += 5.0f * ((dx * dx + dy * dy) * conf_t)
                 + 5.0f * ((dw * dw + dh * dh) * conf_t)
                 + dc * dc;
        }

        // this thread's class half: channels [10+10*half ..+9]; the mask
        // needs the FULL 20-channel target sum -> combine across lane pair.
        {
            float ssum = 0.0f, per_cell = 0.0f;
            const int co = 10 + 10 * half;
#pragma unroll
            for (int k = 0; k < 10; ++k) {
                const float tc = tt[co + k];
                const float pc = pp[co + k];
                ssum     += tc;
                per_cell += tc * tc - pc * pc;
            }
            const float tot = ssum + __shfl_xor(ssum, 1, 64);
            acc += (tot == 1.0f) ? per_cell : 0.0f;
        }

        // stage tile t+GRID into the other buffer (its readers finished
        // before the previous barrier).
        if (havenext) STORE_TILE(cur ^ 1);
        __syncthreads();
        t += GRID;
    }

    // block reduction: wave shuffle -> LDS across 4 waves
    __shared__ float red[BLOCK / 64];
    float v = wave_reduce_sum(acc);
    if (ln == 0) red[wv] = v;
    __syncthreads();
    if (wv == 0) {
        v = (ln < (BLOCK / 64)) ? red[ln] : 0.0f;
        v = wave_reduce_sum(v);
        if (ln == 0) partial[blockIdx.x] = v;
    }
#undef LOAD_TILE
#undef STORE_TILE
}

__global__ __launch_bounds__(256) void yolo_final_kernel(
        const float* __restrict__ partial,
        float* __restrict__ out,
        int n) {
    float acc = 0.0f;
    for (int i = threadIdx.x; i < n; i += 256)
        acc += partial[i];

    __shared__ float red[4];
    const int lane = threadIdx.x & 63;
    const int wid  = threadIdx.x >> 6;
    float v = wave_reduce_sum(acc);
    if (lane == 0) red[wid] = v;
    __syncthreads();
    if (wid == 0) {
        v = (lane < 4) ? red[lane] : 0.0f;
        v = wave_reduce_sum(v);
        if (lane == 0) out[0] = v;
    }
}

extern "C" void kernel_launch(void* const* d_in, const int* in_sizes, int n_in,
                              void* d_out, int out_size, void* d_ws, size_t ws_size,
                              hipStream_t stream) {
    const float* pred = (const float*)d_in[0];
    const float* tgt  = (const float*)d_in[1];
    float* out        = (float*)d_out;
    float* partial    = (float*)d_ws;   // GRID floats = 2 KB

    yolo_partial_kernel<<<GRID, BLOCK, 0, stream>>>(pred, tgt, partial);
    yolo_final_kernel<<<1, 256, 0, stream>>>(partial, out, GRID);
}